// Round 6
// baseline (115.264 us; speedup 1.0000x reference)
//
#include <hip/hip_runtime.h>
#include <stdint.h>

// VectorQuantizer on MI355X (gfx950), round 18: counted-vmcnt 2-deep pipe.
// R16/R17 evidence: two occupancy doublings moved 99->105->97.6 (net ~1.4us)
// -> not TLP-bound. Residual vq_mfma ~35-40us vs ~6us roofline parts is the
// per-phase serial chain: __syncthreads' implicit vmcnt(0) drain + 1-deep
// DMA + 12-deep dependent MFMA chains, exposed 8x in lockstep. This round
// applies T3/T4 (counted vmcnt, the documented fix for the compiler's
// barrier drain): 3 LDS buffers (72KB, still 2 blocks/CU), prologue stages
// ph0+ph1, each phase issues ph+2, barrier = asm "s_waitcnt vmcnt(3)
// lgkmcnt(0)" + raw s_barrier + sched_barrier fences (rule #18). Phase loop
// fully unrolled so wsq hoists to a statically-indexed wq[8][4] (rule #20)
// -> in-loop VMEM = DMAs only, counts exact. Dual accumulator (h0/h1)
// halves MFMA chain depth. Numerics/fragment maps = R11-verified.

#define DDIM 64
#define KCODES 512

typedef __bf16 bf16x8 __attribute__((ext_vector_type(8)));
typedef float f32x4 __attribute__((ext_vector_type(4)));

#define GLOAD_LDS16(gp, lp)                                        \
  __builtin_amdgcn_global_load_lds(                                \
      (const __attribute__((address_space(1))) void*)(gp),         \
      (__attribute__((address_space(3))) void*)(lp), 16, 0, 0)

// ws layout (bytes): WB @0 (192 chunks x 1KB = 196608), wT @196608 (131072),
//                    wsq @327680 (2048) -> need 329728

__device__ __forceinline__ void split3(float f, __bf16& h1, __bf16& h2,
                                       __bf16& h3) {
  h1 = (__bf16)f;
  float r1 = f - (float)h1;   // exact (Sterbenz)
  h2 = (__bf16)r1;
  float r2 = r1 - (float)h2;  // exact
  h3 = (__bf16)r2;            // residual beyond h3 ~ 2^-27 |f|
}

__global__ void vq_prep_m(const float* __restrict__ w,
                          bf16x8* __restrict__ wb,   // [192][64] chunks
                          float* __restrict__ wT, float* __restrict__ wsq,
                          float* __restrict__ loss_out) {
  const int b = blockIdx.x, t = threadIdx.x;
  if (b < 16) {
    // ---- w split -> B-fragment chunks, PHASE-MAJOR layout ----
    // chunk G = ph*24 + ct2*6 + h*3 + s, where ctg = ph*4 + ct2 (16-code
    // tile), h = k-half, s = split. Element (G,L) = split s of
    // B[k=quad*8+32h+j][n=ctg*16+col]  (R11 bench-verified fragment map)
    const int c = b * 256 + t;                // 0..4095
    const int ctg = c >> 7;                   // 16-code tile 0..31
    const int h = (c >> 6) & 1;               // k-half
    const int L = c & 63, quad = L >> 4, col = L & 15;
    bf16x8 v1, v2, v3;
#pragma unroll
    for (int j = 0; j < 8; ++j) {
      float f = w[(quad * 8 + 32 * h + j) * KCODES + ctg * 16 + col];
      __bf16 h1, h2, h3; split3(f, h1, h2, h3);
      v1[j] = h1; v2[j] = h2; v3[j] = h3;
    }
    const int base = (ctg >> 2) * 24 + (ctg & 3) * 6 + h * 3;
    wb[(base + 0) * 64 + L] = v1;
    wb[(base + 1) * 64 + L] = v2;
    wb[(base + 2) * 64 + L] = v3;
  } else {
    // ---- wT transpose + wsq + loss zero ----
    int g = (b - 16) * 256 + t;               // 0..32767 over D*K
    int d = g >> 9, k = g & 511;
    wT[k * DDIM + d] = w[g];
    if (g < KCODES) {
      float s = 0.f;
      for (int dd = 0; dd < DDIM; ++dd) {
        float tv = w[dd * KCODES + g];
        s = fmaf(tv, tv, s);
      }
      wsq[g] = s;
    }
    if (g == 0) *loss_out = 0.f;              // d_out is poisoned each launch
  }
}

__global__ __launch_bounds__(512, 4)
void vq_mfma(const float* __restrict__ x_in, const bf16x8* __restrict__ wb,
             const float* __restrict__ wsq, const float* __restrict__ wT,
             float* __restrict__ out_q, float* __restrict__ out_idx,
             float* __restrict__ loss_out) {
  __shared__ bf16x8 ldsb[4608];               // 3 buffers x 1536 (24KB each)
  __shared__ unsigned long long sm_key[128];
  __shared__ float sm_xsq[128];
  __shared__ unsigned int sm_idx[128];
  __shared__ float sm_loss[128];

  const int t = threadIdx.x, b = blockIdx.x;  // 512 blocks, 128 pts each
  const int wv = t >> 6, L = t & 63, quad = L >> 4, col = L & 15;

  // 24 chunks/phase shared by 8 waves: wave wv stages chunks {i*8 + wv},
  // i=0..2 -> element = i*512 + wv*64 + L. DMA dest is wave-uniform base
  // + L*16 -- exact global_load_lds semantics.
  const int sgbase = wv * 64 + L;

  // ---- prologue: stage phases 0 AND 1 (2-deep pipeline) ----
#pragma unroll
  for (int i = 0; i < 3; ++i)
    GLOAD_LDS16(wb + i * 512 + sgbase, &ldsb[i * 512 + wv * 64]);
#pragma unroll
  for (int i = 0; i < 3; ++i)
    GLOAD_LDS16(wb + 1536 + i * 512 + sgbase, &ldsb[1536 + i * 512 + wv * 64]);

  // ---- load A-fragments straight from x, split3 in-register ----
  // a[split][h]; lane holds A[m=col][k=quad*8+32h+j] of point
  // pt = b*128 + wv*16 + col   (R11 bench-verified A layout)
  bf16x8 a[3][2];
  {
    const float* xr =
        x_in + ((size_t)b * 128 + wv * 16 + col) * DDIM + quad * 8;
    float ssq = 0.f;
#pragma unroll
    for (int h = 0; h < 2; ++h) {
      float4 p0 = *(const float4*)(xr + 32 * h);
      float4 p1 = *(const float4*)(xr + 32 * h + 4);
      float f[8] = {p0.x, p0.y, p0.z, p0.w, p1.x, p1.y, p1.z, p1.w};
      bf16x8 v1, v2, v3;
#pragma unroll
      for (int j = 0; j < 8; ++j) {
        ssq = fmaf(f[j], f[j], ssq);
        __bf16 h1, h2, h3; split3(f[j], h1, h2, h3);
        v1[j] = h1; v2[j] = h2; v3[j] = h3;
      }
      a[0][h] = v1; a[1][h] = v2; a[2][h] = v3;
    }
    // combine the 4 quads (lanes col, col+16, col+32, col+48 = same point)
    ssq += __shfl_xor(ssq, 16, 64);
    ssq += __shfl_xor(ssq, 32, 64);
    if (quad == 0) sm_xsq[wv * 16 + col] = ssq;  // fp32-exact
  }

  // ---- hoist ALL wsq values (32 regs, statically indexed after unroll) ----
  float wq[8][4];
#pragma unroll
  for (int p = 0; p < 8; ++p)
#pragma unroll
    for (int c = 0; c < 4; ++c) wq[p][c] = wsq[p * 64 + c * 16 + col];

  float best[4];
  int bidx[4];
#pragma unroll
  for (int r = 0; r < 4; ++r) { best[r] = 3.0e38f; bidx[r] = 0; }

  // ---- main loop, FULLY UNROLLED, counted-vmcnt barriers (T3/T4) ----
  // In-loop VMEM = staging DMAs only (wsq hoisted). FIFO audit:
  // issues: D0,D1 (prologue), D(ph+2) in phase ph (ph<6).
  // top of phase ph: outstanding <= {D(ph), D(ph+1)} = 6; vmcnt(3)
  // drains D(ph) (oldest 3), leaves D(ph+1) in flight. ph=7: vmcnt(0).
#pragma unroll
  for (int ph = 0; ph < 8; ++ph) {
    if (ph < 7)
      asm volatile("s_waitcnt vmcnt(3) lgkmcnt(0)" ::: "memory");
    else
      asm volatile("s_waitcnt vmcnt(0) lgkmcnt(0)" ::: "memory");
    __builtin_amdgcn_sched_barrier(0);
    __builtin_amdgcn_s_barrier();
    __builtin_amdgcn_sched_barrier(0);

    // issue phase ph+2 staging into buf[(ph+2)%3]. Safe: its last readers
    // were phase ph-1, all waves past that via this barrier.
    if (ph < 6) {
      const bf16x8* src = wb + (ph + 2) * 1536 + sgbase;
      bf16x8* dstl = &ldsb[((ph + 2) % 3) * 1536 + wv * 64];
#pragma unroll
      for (int i = 0; i < 3; ++i)
        GLOAD_LDS16(src + i * 512, dstl + i * 512);
    }

    const bf16x8* bufp = ldsb + (ph % 3) * 1536;
    __builtin_amdgcn_s_setprio(1);
#pragma unroll
    for (int ct = 0; ct < 4; ++ct) {
      // dual accumulator: h=0 -> aA, h=1 -> aB (2x6 chains, not 1x12)
      f32x4 aA = {0.f, 0.f, 0.f, 0.f};
      f32x4 aB = {0.f, 0.f, 0.f, 0.f};
      {
        bf16x8 b0 = bufp[(ct * 6 + 0) * 64 + L];
        bf16x8 b1 = bufp[(ct * 6 + 1) * 64 + L];
        bf16x8 b2 = bufp[(ct * 6 + 2) * 64 + L];
        aA = __builtin_amdgcn_mfma_f32_16x16x32_bf16(a[0][0], b0, aA, 0, 0, 0);
        aA = __builtin_amdgcn_mfma_f32_16x16x32_bf16(a[0][0], b1, aA, 0, 0, 0);
        aA = __builtin_amdgcn_mfma_f32_16x16x32_bf16(a[1][0], b0, aA, 0, 0, 0);
        aA = __builtin_amdgcn_mfma_f32_16x16x32_bf16(a[1][0], b1, aA, 0, 0, 0);
        aA = __builtin_amdgcn_mfma_f32_16x16x32_bf16(a[0][0], b2, aA, 0, 0, 0);
        aA = __builtin_amdgcn_mfma_f32_16x16x32_bf16(a[2][0], b0, aA, 0, 0, 0);
      }
      {
        bf16x8 b0 = bufp[(ct * 6 + 3) * 64 + L];
        bf16x8 b1 = bufp[(ct * 6 + 4) * 64 + L];
        bf16x8 b2 = bufp[(ct * 6 + 5) * 64 + L];
        aB = __builtin_amdgcn_mfma_f32_16x16x32_bf16(a[0][1], b0, aB, 0, 0, 0);
        aB = __builtin_amdgcn_mfma_f32_16x16x32_bf16(a[0][1], b1, aB, 0, 0, 0);
        aB = __builtin_amdgcn_mfma_f32_16x16x32_bf16(a[1][1], b0, aB, 0, 0, 0);
        aB = __builtin_amdgcn_mfma_f32_16x16x32_bf16(a[1][1], b1, aB, 0, 0, 0);
        aB = __builtin_amdgcn_mfma_f32_16x16x32_bf16(a[0][1], b2, aB, 0, 0, 0);
        aB = __builtin_amdgcn_mfma_f32_16x16x32_bf16(a[2][1], b0, aB, 0, 0, 0);
      }
      f32x4 acc = aA + aB;
      // dist + per-lane argmin; C layout: pt = quad*4 + r, code = col
      int code = ph * 64 + ct * 16 + col;
      float wqv = wq[ph][ct];
#pragma unroll
      for (int r = 0; r < 4; ++r) {
        float d0 = fmaf(acc[r], -2.0f, wqv);
        if (d0 < best[r]) { best[r] = d0; bidx[r] = code; }
      }
    }
    __builtin_amdgcn_s_setprio(0);
  }

  // ---- cross-lane reduce over the 16 cols; idx in low bits -> lowest idx ----
#pragma unroll
  for (int r = 0; r < 4; ++r) {
    unsigned int ub = __float_as_uint(best[r]);
    ub = (ub & 0x80000000u) ? ~ub : (ub | 0x80000000u);
    unsigned long long key = ((unsigned long long)ub << 32) |
                             (unsigned long long)(unsigned int)bidx[r];
#pragma unroll
    for (int off = 1; off < 16; off <<= 1) {
      unsigned long long o = __shfl_xor(key, off, 64);
      key = o < key ? o : key;
    }
    if (col == 0)
      sm_key[wv * 16 + quad * 4 + r] = key;
  }
  __syncthreads();

  if (t < 128) {
    unsigned long long k = sm_key[t];
    unsigned int idx = (unsigned int)k;
    sm_idx[t] = idx;
    out_idx[(size_t)b * 128 + t] = (float)idx;
    unsigned int u = (unsigned int)(k >> 32);
    u = (u & 0x80000000u) ? (u & 0x7FFFFFFFu) : ~u;
    // ||x-q||^2 = ||x||^2 + (||q||^2 - 2 x.q), pre-scaled by 1.25/(N*D)
    sm_loss[t] = (__uint_as_float(u) + sm_xsq[t]) * (1.25f / 4194304.0f);
  }
  __syncthreads();

  // ---- fused epilogue: gather code rows, coalesced 128x64 out tile ----
  float4* dst = (float4*)(out_q + (size_t)b * 8192);
#pragma unroll
  for (int i = 0; i < 4; ++i) {
    int e4 = i * 512 + t;
    int p2 = e4 >> 4, d4 = e4 & 15;
    unsigned int idx = sm_idx[p2];                            // LDS broadcast
    dst[e4] = ((const float4*)(wT + (size_t)idx * DDIM))[d4]; // L2-hot
  }

  if (t < 64) {
    float s = sm_loss[t] + sm_loss[t + 64];
#pragma unroll
    for (int off = 32; off > 0; off >>= 1) s += __shfl_down(s, off);
    if (t == 0) atomicAdd(loss_out, s);       // 512 adds total
  }
}

// ---------------- fallback (R9 kernels, proven) ----------------

__global__ void vq_prep(const float* __restrict__ w, float* __restrict__ wT,
                        float* __restrict__ wsq, float* __restrict__ loss_out) {
  int g = blockIdx.x * 256 + threadIdx.x;
  int d = g >> 9, k = g & 511;
  wT[k * DDIM + d] = w[g];
  if (g < KCODES) {
    float s = 0.f;
    for (int dd = 0; dd < DDIM; ++dd) {
      float t = w[dd * KCODES + g];
      s = fmaf(t, t, s);
    }
    wsq[g] = s;
  }
  if (g == 0) *loss_out = 0.f;
}

__global__ __launch_bounds__(512, 8)
void vq_main(const float* __restrict__ x_in, const float* __restrict__ w,
             const float* __restrict__ wT, const float* __restrict__ wsq,
             float* __restrict__ out_q, float* __restrict__ out_idx,
             float* __restrict__ loss_out) {
  __shared__ float xs[DDIM][65];
  __shared__ unsigned long long sm_key[8][64];
  __shared__ unsigned int sm_idx[64];
  __shared__ float sm_sx[64];
  __shared__ float sm_loss[64];

  const int t = threadIdx.x;
  const int pb = blockIdx.x;
  const int wv = __builtin_amdgcn_readfirstlane(t >> 6);
  const int lane = t & 63;

  {
    const float4* src = (const float4*)(x_in + (size_t)pb * 4096);
#pragma unroll
    for (int i = 0; i < 2; ++i) {
      int e4 = i * 512 + t;
      float4 v = src[e4];
      int e = e4 << 2;
      int pt = e >> 6, d = e & 63;
      xs[d][pt] = v.x; xs[d + 1][pt] = v.y;
      xs[d + 2][pt] = v.z; xs[d + 3][pt] = v.w;
    }
  }
  __syncthreads();

  const int kbase = wv << 6;
  float best = 3.0e38f;
  int bidx = 0;
  float sx = 0.f;

#pragma unroll 1
  for (int kb = 0; kb < 2; ++kb) {
    const int k0 = kbase + (kb << 5);
    const float* wp = w + k0;
    float acc[32];
#pragma unroll
    for (int c = 0; c < 32; ++c) acc[c] = 0.f;
#pragma unroll 1
    for (int d8 = 0; d8 < 8; ++d8) {
      float xv[8];
#pragma unroll
      for (int dd = 0; dd < 8; ++dd) xv[dd] = xs[(d8 << 3) + dd][lane];
      if (wv == 0 && kb == 0) {
#pragma unroll
        for (int dd = 0; dd < 8; ++dd) sx = fmaf(xv[dd], xv[dd], sx);
      }
#pragma unroll
      for (int dd = 0; dd < 8; ++dd) {
        const float* wd = wp + (((d8 << 3) + dd) << 9);
#pragma unroll
        for (int c = 0; c < 32; ++c) acc[c] = fmaf(wd[c], xv[dd], acc[c]);
      }
    }
#pragma unroll
    for (int c = 0; c < 32; ++c) {
      float dist = fmaf(acc[c], -2.0f, wsq[k0 + c]);
      if (dist < best) { best = dist; bidx = k0 + c; }
    }
  }

  unsigned int ub = __float_as_uint(best);
  ub = (ub & 0x80000000u) ? ~ub : (ub | 0x80000000u);
  sm_key[wv][lane] =
      ((unsigned long long)ub << 32) | (unsigned long long)(unsigned int)bidx;
  if (wv == 0) sm_sx[lane] = sx;
  __syncthreads();

  if (t < 64) {
    unsigned long long k = sm_key[0][t];
#pragma unroll
    for (int wi = 1; wi < 8; ++wi) {
      unsigned long long k2 = sm_key[wi][t];
      k = k2 < k ? k2 : k;
    }
    unsigned int idx = (unsigned int)k;
    sm_idx[t] = idx;
    out_idx[((size_t)pb << 6) + t] = (float)idx;
    unsigned int u = (unsigned int)(k >> 32);
    u = (u & 0x80000000u) ? (u & 0x7FFFFFFFu) : ~u;
    sm_loss[t] = (__uint_as_float(u) + sm_sx[t]) * (1.25f / 4194304.0f);
  }
  __syncthreads();

  float4* dst = (float4*)(out_q + (size_t)pb * 4096);
#pragma unroll
  for (int i = 0; i < 2; ++i) {
    int e4 = i * 512 + t;
    int p2 = e4 >> 4, d4 = e4 & 15;
    unsigned int idx = sm_idx[p2];
    dst[e4] = ((const float4*)(wT + (size_t)idx * DDIM))[d4];
  }

  if (t < 64) {
    float s = sm_loss[t];
#pragma unroll
    for (int off = 32; off > 0; off >>= 1) s += __shfl_down(s, off);
    if (t == 0) atomicAdd(loss_out, s);
  }
}

extern "C" void kernel_launch(void* const* d_in, const int* in_sizes, int n_in,
                              void* d_out, int out_size, void* d_ws, size_t ws_size,
                              hipStream_t stream) {
  const float* x = (const float*)d_in[0];  // (64,32,32,64) fp32
  const float* w = (const float*)d_in[1];  // (64,512) fp32

  float* out_q = (float*)d_out;            // 4194304 floats
  float* out_idx = out_q + 4194304;        // 65536 floats (indices)
  float* loss_out = out_q + 4259840;       // 1 float

  char* ws = (char*)d_ws;
  if (ws_size >= 329728) {
    bf16x8* wbp = (bf16x8*)(ws);
    float* wT = (float*)(ws + 196608);
    float* wsq = (float*)(ws + 327680);
    vq_prep_m<<<144, 256, 0, stream>>>(w, wbp, wT, wsq, loss_out);
    vq_mfma<<<512, 512, 0, stream>>>(x, wbp, wsq, wT, out_q, out_idx,
                                     loss_out);
  } else {
    float* wT = (float*)(ws);
    float* wsq = (float*)(ws + 131072);
    vq_prep<<<128, 256, 0, stream>>>(w, wT, wsq, loss_out);
    vq_main<<<1024, 512, 0, stream>>>(x, w, wT, wsq, out_q, out_idx,
                                      loss_out);
  }
}

// Round 8
// 96.250 us; speedup vs baseline: 1.1975x; 1.1975x over previous
//
#include <hip/hip_runtime.h>
#include <stdint.h>

// VectorQuantizer on MI355X (gfx950), round 20: resubmit of R19 (infra
// failure last round -- container died, kernel never ran).
// R19 = R17 base (97.6us verified) + two audited deltas:
// (1) prep_m wsq: was a 64-iter strided serial tail on 512 threads between
//     fill and vq_mfma; now 8 blocks x 4 thr/code x 16 elems + shfl_xor
//     tree (deterministic, loads unrolled/independent).
// (2) ct loop: dual accumulator (h=0->aA, h=1->aB, one add) -- chain depth
//     12 -> 6, +16 VGPR (~90 < 128 cap, no spill).
// R18 post-mortem context: launch_bounds(512,4) caps VGPR at 128; wq[8][4]
// hoist + full unroll spilled (VGPR 64, WRITE 104MB scratch). FIFO audit:
// per-phase wsq loads are NEWER than staging DMA, so compiler's wsq wait
// drains DMA a phase early -- counted vmcnt has nothing to save here.
// Everything else byte-identical to R17. Fragment maps R11-verified.

#define DDIM 64
#define KCODES 512

typedef __bf16 bf16x8 __attribute__((ext_vector_type(8)));
typedef float f32x4 __attribute__((ext_vector_type(4)));

#define GLOAD_LDS16(gp, lp)                                        \
  __builtin_amdgcn_global_load_lds(                                \
      (const __attribute__((address_space(1))) void*)(gp),         \
      (__attribute__((address_space(3))) void*)(lp), 16, 0, 0)

// ws layout (bytes): WB @0 (192 chunks x 1KB = 196608), wT @196608 (131072),
//                    wsq @327680 (2048) -> need 329728

__device__ __forceinline__ void split3(float f, __bf16& h1, __bf16& h2,
                                       __bf16& h3) {
  h1 = (__bf16)f;
  float r1 = f - (float)h1;   // exact (Sterbenz)
  h2 = (__bf16)r1;
  float r2 = r1 - (float)h2;  // exact
  h3 = (__bf16)r2;            // residual beyond h3 ~ 2^-27 |f|
}

__global__ void vq_prep_m(const float* __restrict__ w,
                          bf16x8* __restrict__ wb,   // [192][64] chunks
                          float* __restrict__ wT, float* __restrict__ wsq,
                          float* __restrict__ loss_out) {
  const int b = blockIdx.x, t = threadIdx.x;
  if (b < 16) {
    // ---- w split -> B-fragment chunks, PHASE-MAJOR layout ----
    // chunk G = ph*24 + ct2*6 + h*3 + s, where ctg = ph*4 + ct2 (16-code
    // tile), h = k-half, s = split. Element (G,L) = split s of
    // B[k=quad*8+32h+j][n=ctg*16+col]  (R11 bench-verified fragment map)
    const int c = b * 256 + t;                // 0..4095
    const int ctg = c >> 7;                   // 16-code tile 0..31
    const int h = (c >> 6) & 1;               // k-half
    const int L = c & 63, quad = L >> 4, col = L & 15;
    bf16x8 v1, v2, v3;
#pragma unroll
    for (int j = 0; j < 8; ++j) {
      float f = w[(quad * 8 + 32 * h + j) * KCODES + ctg * 16 + col];
      __bf16 h1, h2, h3; split3(f, h1, h2, h3);
      v1[j] = h1; v2[j] = h2; v3[j] = h3;
    }
    const int base = (ctg >> 2) * 24 + (ctg & 3) * 6 + h * 3;
    wb[(base + 0) * 64 + L] = v1;
    wb[(base + 1) * 64 + L] = v2;
    wb[(base + 2) * 64 + L] = v3;
  } else if (b < 144) {
    // ---- wT transpose + loss zero ----
    int g = (b - 16) * 256 + t;               // 0..32767 over D*K
    int d = g >> 9, k = g & 511;
    wT[k * DDIM + d] = w[g];
    if (g == 0) *loss_out = 0.f;              // d_out is poisoned each launch
  } else {
    // ---- wsq: 4 threads per code, 16 elems each, shfl tree (parallel,
    // no 64-iter serial tail) ----
    int i = (b - 144) * 256 + t;              // 0..2047
    int k = i >> 2, p = i & 3;
    float s = 0.f;
#pragma unroll
    for (int dd = 0; dd < 16; ++dd) {
      float tv = w[(p * 16 + dd) * KCODES + k];
      s = fmaf(tv, tv, s);
    }
    s += __shfl_xor(s, 1, 64);
    s += __shfl_xor(s, 2, 64);
    if (p == 0) wsq[k] = s;
  }
}

__global__ __launch_bounds__(512, 4)
void vq_mfma(const float* __restrict__ x_in, const bf16x8* __restrict__ wb,
             const float* __restrict__ wsq, const float* __restrict__ wT,
             float* __restrict__ out_q, float* __restrict__ out_idx,
             float* __restrict__ loss_out) {
  __shared__ bf16x8 ldsb[3072];               // 2 buffers x 1536 (24KB each)
  __shared__ unsigned long long sm_key[128];
  __shared__ float sm_xsq[128];
  __shared__ unsigned int sm_idx[128];
  __shared__ float sm_loss[128];

  const int t = threadIdx.x, b = blockIdx.x;  // 512 blocks, 128 pts each
  const int wv = t >> 6, L = t & 63, quad = L >> 4, col = L & 15;

  // 24 chunks/phase shared by 8 waves: wave wv stages chunks {i*8 + wv},
  // i=0..2 -> element = i*512 + wv*64 + L. DMA dest is wave-uniform base
  // + L*16 -- exact global_load_lds semantics.
  const int sgbase = wv * 64 + L;

  // ---- issue phase-0 staging DMA FIRST (overlaps x prologue VALU) ----
#pragma unroll
  for (int i = 0; i < 3; ++i)
    GLOAD_LDS16(wb + i * 512 + sgbase, &ldsb[i * 512 + wv * 64]);

  // ---- load A-fragments straight from x, split3 in-register ----
  // a[split][h]; lane holds A[m=col][k=quad*8+32h+j] of point
  // pt = b*128 + wv*16 + col   (R11 bench-verified A layout)
  bf16x8 a[3][2];
  {
    const float* xr =
        x_in + ((size_t)b * 128 + wv * 16 + col) * DDIM + quad * 8;
    float ssq = 0.f;
#pragma unroll
    for (int h = 0; h < 2; ++h) {
      float4 p0 = *(const float4*)(xr + 32 * h);
      float4 p1 = *(const float4*)(xr + 32 * h + 4);
      float f[8] = {p0.x, p0.y, p0.z, p0.w, p1.x, p1.y, p1.z, p1.w};
      bf16x8 v1, v2, v3;
#pragma unroll
      for (int j = 0; j < 8; ++j) {
        ssq = fmaf(f[j], f[j], ssq);
        __bf16 h1, h2, h3; split3(f[j], h1, h2, h3);
        v1[j] = h1; v2[j] = h2; v3[j] = h3;
      }
      a[0][h] = v1; a[1][h] = v2; a[2][h] = v3;
    }
    // combine the 4 quads (lanes col, col+16, col+32, col+48 = same point)
    ssq += __shfl_xor(ssq, 16, 64);
    ssq += __shfl_xor(ssq, 32, 64);
    if (quad == 0) sm_xsq[wv * 16 + col] = ssq;  // fp32-exact
  }

  float best[4];
  int bidx[4];
#pragma unroll
  for (int r = 0; r < 4; ++r) { best[r] = 3.0e38f; bidx[r] = 0; }

#pragma unroll 1
  for (int ph = 0; ph < 8; ++ph) {
    // Compiler emits s_waitcnt vmcnt(0) before s_barrier -> buf[ph&1]'s DMA
    // (issued one phase ago, L2-hot) is complete for every wave here.
    __syncthreads();
    // prefetch this phase's wsq values (named scalars; issued BEFORE the
    // DMA so their wait leaves the staging loads in flight)
    float wq0 = wsq[ph * 64 + col];
    float wq1 = wsq[ph * 64 + 16 + col];
    float wq2 = wsq[ph * 64 + 32 + col];
    float wq3 = wsq[ph * 64 + 48 + col];
    // issue next phase's staging DMA into the other buffer. Safe: that
    // buffer was last read in phase ph-1, before this barrier.
    if (ph < 7) {
      const bf16x8* src = wb + (ph + 1) * 1536 + sgbase;
      bf16x8* dst = &ldsb[((ph + 1) & 1) * 1536 + wv * 64];
#pragma unroll
      for (int i = 0; i < 3; ++i)
        GLOAD_LDS16(src + i * 512, dst + i * 512);
    }

    const bf16x8* bufp = ldsb + (ph & 1) * 1536;
    __builtin_amdgcn_s_setprio(1);
#pragma unroll
    for (int ct = 0; ct < 4; ++ct) {
      // dual accumulator: h=0 -> aA, h=1 -> aB (2x6 chains, not 1x12)
      f32x4 aA = {0.f, 0.f, 0.f, 0.f};
      f32x4 aB = {0.f, 0.f, 0.f, 0.f};
      {
        bf16x8 b0 = bufp[(ct * 6 + 0) * 64 + L];
        bf16x8 b1 = bufp[(ct * 6 + 1) * 64 + L];
        bf16x8 b2 = bufp[(ct * 6 + 2) * 64 + L];
        // 6-term split (x1w1,x1w2,x2w1,x2w2,x1w3,x3w1)
        aA = __builtin_amdgcn_mfma_f32_16x16x32_bf16(a[0][0], b0, aA, 0, 0, 0);
        aA = __builtin_amdgcn_mfma_f32_16x16x32_bf16(a[0][0], b1, aA, 0, 0, 0);
        aA = __builtin_amdgcn_mfma_f32_16x16x32_bf16(a[1][0], b0, aA, 0, 0, 0);
        aA = __builtin_amdgcn_mfma_f32_16x16x32_bf16(a[1][0], b1, aA, 0, 0, 0);
        aA = __builtin_amdgcn_mfma_f32_16x16x32_bf16(a[0][0], b2, aA, 0, 0, 0);
        aA = __builtin_amdgcn_mfma_f32_16x16x32_bf16(a[2][0], b0, aA, 0, 0, 0);
      }
      {
        bf16x8 b0 = bufp[(ct * 6 + 3) * 64 + L];
        bf16x8 b1 = bufp[(ct * 6 + 4) * 64 + L];
        bf16x8 b2 = bufp[(ct * 6 + 5) * 64 + L];
        aB = __builtin_amdgcn_mfma_f32_16x16x32_bf16(a[0][1], b0, aB, 0, 0, 0);
        aB = __builtin_amdgcn_mfma_f32_16x16x32_bf16(a[0][1], b1, aB, 0, 0, 0);
        aB = __builtin_amdgcn_mfma_f32_16x16x32_bf16(a[1][1], b0, aB, 0, 0, 0);
        aB = __builtin_amdgcn_mfma_f32_16x16x32_bf16(a[1][1], b1, aB, 0, 0, 0);
        aB = __builtin_amdgcn_mfma_f32_16x16x32_bf16(a[0][1], b2, aB, 0, 0, 0);
        aB = __builtin_amdgcn_mfma_f32_16x16x32_bf16(a[2][1], b0, aB, 0, 0, 0);
      }
      f32x4 acc = aA + aB;
      // dist + per-lane argmin; C layout: pt = quad*4 + r, code = col
      int code = ph * 64 + ct * 16 + col;
      float wq = (ct == 0) ? wq0 : (ct == 1) ? wq1 : (ct == 2) ? wq2 : wq3;
#pragma unroll
      for (int r = 0; r < 4; ++r) {
        float d0 = fmaf(acc[r], -2.0f, wq);
        if (d0 < best[r]) { best[r] = d0; bidx[r] = code; }
      }
    }
    __builtin_amdgcn_s_setprio(0);
  }

  // ---- cross-lane reduce over the 16 cols; idx in low bits -> lowest idx ----
#pragma unroll
  for (int r = 0; r < 4; ++r) {
    unsigned int ub = __float_as_uint(best[r]);
    ub = (ub & 0x80000000u) ? ~ub : (ub | 0x80000000u);
    unsigned long long key = ((unsigned long long)ub << 32) |
                             (unsigned long long)(unsigned int)bidx[r];
#pragma unroll
    for (int off = 1; off < 16; off <<= 1) {
      unsigned long long o = __shfl_xor(key, off, 64);
      key = o < key ? o : key;
    }
    if (col == 0)
      sm_key[wv * 16 + quad * 4 + r] = key;
  }
  __syncthreads();

  if (t < 128) {
    unsigned long long k = sm_key[t];
    unsigned int idx = (unsigned int)k;
    sm_idx[t] = idx;
    out_idx[(size_t)b * 128 + t] = (float)idx;
    unsigned int u = (unsigned int)(k >> 32);
    u = (u & 0x80000000u) ? (u & 0x7FFFFFFFu) : ~u;
    // ||x-q||^2 = ||x||^2 + (||q||^2 - 2 x.q), pre-scaled by 1.25/(N*D)
    sm_loss[t] = (__uint_as_float(u) + sm_xsq[t]) * (1.25f / 4194304.0f);
  }
  __syncthreads();

  // ---- fused epilogue: gather code rows, coalesced 128x64 out tile ----
  float4* dst = (float4*)(out_q + (size_t)b * 8192);
#pragma unroll
  for (int i = 0; i < 4; ++i) {
    int e4 = i * 512 + t;
    int p2 = e4 >> 4, d4 = e4 & 15;
    unsigned int idx = sm_idx[p2];                            // LDS broadcast
    dst[e4] = ((const float4*)(wT + (size_t)idx * DDIM))[d4]; // L2-hot
  }

  if (t < 64) {
    float s = sm_loss[t] + sm_loss[t + 64];
#pragma unroll
    for (int off = 32; off > 0; off >>= 1) s += __shfl_down(s, off);
    if (t == 0) atomicAdd(loss_out, s);       // 512 adds total
  }
}

// ---------------- fallback (R9 kernels, proven) ----------------

__global__ void vq_prep(const float* __restrict__ w, float* __restrict__ wT,
                        float* __restrict__ wsq, float* __restrict__ loss_out) {
  int g = blockIdx.x * 256 + threadIdx.x;
  int d = g >> 9, k = g & 511;
  wT[k * DDIM + d] = w[g];
  if (g < KCODES) {
    float s = 0.f;
    for (int dd = 0; dd < DDIM; ++dd) {
      float t = w[dd * KCODES + g];
      s = fmaf(t, t, s);
    }
    wsq[g] = s;
  }
  if (g == 0) *loss_out = 0.f;
}

__global__ __launch_bounds__(512, 8)
void vq_main(const float* __restrict__ x_in, const float* __restrict__ w,
             const float* __restrict__ wT, const float* __restrict__ wsq,
             float* __restrict__ out_q, float* __restrict__ out_idx,
             float* __restrict__ loss_out) {
  __shared__ float xs[DDIM][65];
  __shared__ unsigned long long sm_key[8][64];
  __shared__ unsigned int sm_idx[64];
  __shared__ float sm_sx[64];
  __shared__ float sm_loss[64];

  const int t = threadIdx.x;
  const int pb = blockIdx.x;
  const int wv = __builtin_amdgcn_readfirstlane(t >> 6);
  const int lane = t & 63;

  {
    const float4* src = (const float4*)(x_in + (size_t)pb * 4096);
#pragma unroll
    for (int i = 0; i < 2; ++i) {
      int e4 = i * 512 + t;
      float4 v = src[e4];
      int e = e4 << 2;
      int pt = e >> 6, d = e & 63;
      xs[d][pt] = v.x; xs[d + 1][pt] = v.y;
      xs[d + 2][pt] = v.z; xs[d + 3][pt] = v.w;
    }
  }
  __syncthreads();

  const int kbase = wv << 6;
  float best = 3.0e38f;
  int bidx = 0;
  float sx = 0.f;

#pragma unroll 1
  for (int kb = 0; kb < 2; ++kb) {
    const int k0 = kbase + (kb << 5);
    const float* wp = w + k0;
    float acc[32];
#pragma unroll
    for (int c = 0; c < 32; ++c) acc[c] = 0.f;
#pragma unroll 1
    for (int d8 = 0; d8 < 8; ++d8) {
      float xv[8];
#pragma unroll
      for (int dd = 0; dd < 8; ++dd) xv[dd] = xs[(d8 << 3) + dd][lane];
      if (wv == 0 && kb == 0) {
#pragma unroll
        for (int dd = 0; dd < 8; ++dd) sx = fmaf(xv[dd], xv[dd], sx);
      }
#pragma unroll
      for (int dd = 0; dd < 8; ++dd) {
        const float* wd = wp + (((d8 << 3) + dd) << 9);
#pragma unroll
        for (int c = 0; c < 32; ++c) acc[c] = fmaf(wd[c], xv[dd], acc[c]);
      }
    }
#pragma unroll
    for (int c = 0; c < 32; ++c) {
      float dist = fmaf(acc[c], -2.0f, wsq[k0 + c]);
      if (dist < best) { best = dist; bidx = k0 + c; }
    }
  }

  unsigned int ub = __float_as_uint(best);
  ub = (ub & 0x80000000u) ? ~ub : (ub | 0x80000000u);
  sm_key[wv][lane] =
      ((unsigned long long)ub << 32) | (unsigned long long)(unsigned int)bidx;
  if (wv == 0) sm_sx[lane] = sx;
  __syncthreads();

  if (t < 64) {
    unsigned long long k = sm_key[0][t];
#pragma unroll
    for (int wi = 1; wi < 8; ++wi) {
      unsigned long long k2 = sm_key[wi][t];
      k = k2 < k ? k2 : k;
    }
    unsigned int idx = (unsigned int)k;
    sm_idx[t] = idx;
    out_idx[((size_t)pb << 6) + t] = (float)idx;
    unsigned int u = (unsigned int)(k >> 32);
    u = (u & 0x80000000u) ? (u & 0x7FFFFFFFu) : ~u;
    sm_loss[t] = (__uint_as_float(u) + sm_sx[t]) * (1.25f / 4194304.0f);
  }
  __syncthreads();

  float4* dst = (float4*)(out_q + (size_t)pb * 4096);
#pragma unroll
  for (int i = 0; i < 2; ++i) {
    int e4 = i * 512 + t;
    int p2 = e4 >> 4, d4 = e4 & 15;
    unsigned int idx = sm_idx[p2];
    dst[e4] = ((const float4*)(wT + (size_t)idx * DDIM))[d4];
  }

  if (t < 64) {
    float s = sm_loss[t];
#pragma unroll
    for (int off = 32; off > 0; off >>= 1) s += __shfl_down(s, off);
    if (t == 0) atomicAdd(loss_out, s);
  }
}

extern "C" void kernel_launch(void* const* d_in, const int* in_sizes, int n_in,
                              void* d_out, int out_size, void* d_ws, size_t ws_size,
                              hipStream_t stream) {
  const float* x = (const float*)d_in[0];  // (64,32,32,64) fp32
  const float* w = (const float*)d_in[1];  // (64,512) fp32

  float* out_q = (float*)d_out;            // 4194304 floats
  float* out_idx = out_q + 4194304;        // 65536 floats (indices)
  float* loss_out = out_q + 4259840;       // 1 float

  char* ws = (char*)d_ws;
  if (ws_size >= 329728) {
    bf16x8* wbp = (bf16x8*)(ws);
    float* wT = (float*)(ws + 196608);
    float* wsq = (float*)(ws + 327680);
    vq_prep_m<<<152, 256, 0, stream>>>(w, wbp, wT, wsq, loss_out);
    vq_mfma<<<512, 512, 0, stream>>>(x, wbp, wsq, wT, out_q, out_idx,
                                     loss_out);
  } else {
    float* wT = (float*)(ws);
    float* wsq = (float*)(ws + 131072);
    vq_prep<<<128, 256, 0, stream>>>(w, wT, wsq, loss_out);
    vq_main<<<1024, 512, 0, stream>>>(x, w, wT, wsq, out_q, out_idx,
                                      loss_out);
  }
}